// Round 4
// baseline (115.009 us; speedup 1.0000x reference)
//
#include <hip/hip_runtime.h>

#define NODES 100000
#define NTAG  10000
#define NE    4
#define ND    32
#define NB    524288

constexpr int TPB   = 256;
constexpr int NBLK  = 1024;           // main kernel: 4 blocks/CU (keeps per-CU L1 node sets ~27KB)
constexpr int GPB   = TPB / 8;        // 32 sample-groups per block
constexpr int BNODE = 13;             // nodes per bucket (13*512B = 6.7KB working set)
constexpr int NBUCK = (NODES + BNODE - 1) / BNODE;  // 7693
constexpr int CAP   = 256;            // slots/bucket; mean 136, sd 11.7 -> +10 sigma
constexpr int NPART = NBLK;           // loss partials (one per block, plain store)

// ws layout
constexpr size_t OFF_REC  = 32 * 1024;                              // cnt[NBUCK] ints first
constexpr size_t OFF_LOSS = OFF_REC + (size_t)NBUCK * CAP * 4;      // 7,910,400 (64B aligned)
constexpr size_t WS_NEED  = OFF_LOSS + (size_t)NPART * 8;

// ============================ bucketed path ================================

__global__ __launch_bounds__(TPB) void init_kernel(const float* __restrict__ act,
                                                   float* __restrict__ out,
                                                   int* __restrict__ cnt) {
    int i = blockIdx.x * TPB + threadIdx.x;
    if (i < NODES * NE) out[1 + i] = act[i];
    if (i < NBUCK)      cnt[i] = 0;
}

__global__ __launch_bounds__(TPB) void scatter_kernel(
    const int* __restrict__ pos_node, const int* __restrict__ pos_tag,
    const int* __restrict__ neg_node, const int* __restrict__ neg_tag,
    int* __restrict__ cnt, uint32_t* __restrict__ rec)
{
    const int i = blockIdx.x * TPB + threadIdx.x;   // grid == 2*NB exactly
    const bool is_pos = i < NB;
    const int  b    = is_pos ? i : i - NB;
    const int  node = is_pos ? pos_node[b] : neg_node[b];
    const int  tag  = is_pos ? pos_tag[b]  : neg_tag[b];
    const int  bk   = node / BNODE;
    const int  p    = atomicAdd(&cnt[bk], 1);
    if (p < CAP)    // statistically impossible to overflow (+10 sigma); inputs are fixed
        rec[(size_t)bk * CAP + p] = ((uint32_t)node << 15) | ((uint32_t)tag << 1) | (is_pos ? 1u : 0u);
}

__global__ __launch_bounds__(TPB) void main_kernel(
    const float* __restrict__ tag_table, const float* __restrict__ node_tables,
    const int* __restrict__ cnt, const uint32_t* __restrict__ rec,
    float* __restrict__ out, double* __restrict__ loss_part)
{
    __shared__ uint32_t hist[BNODE * NE];   // per-bucket activate counts
    __shared__ double sm[TPB / 64];

    const int tid = threadIdx.x;
    const int g   = tid & 7;                 // lane within 8-lane sample group
    const int grp = tid >> 3;
    const uint32_t goff = (uint32_t)g << 4;  // byte offset of lane's float4 in a 128B row

    const char* tagb  = (const char*)tag_table;
    const char* nodb0 = (const char*)node_tables;
    const char* nodb1 = nodb0 + (size_t)NODES * 128;
    const char* nodb2 = nodb1 + (size_t)NODES * 128;
    const char* nodb3 = nodb2 + (size_t)NODES * 128;

    float local = 0.f;

    for (int bk = blockIdx.x; bk < NBUCK; bk += NBLK) {
        const int n = min(cnt[bk], CAP);
        const uint32_t* __restrict__ recs = rec + (size_t)bk * CAP;
        const uint32_t nbase = (uint32_t)bk * BNODE;

        if (tid < BNODE * NE) hist[tid] = 0;
        __syncthreads();

        // pipelined: rows for sample j+GPB issued while computing sample j
        int j = grp;
        float4 ct, cr0, cr1, cr2, cr3;
        uint32_t crec = 0;
        if (j < n) {
            crec = recs[j];
            const uint32_t node = crec >> 15, tag = (crec >> 1) & 0x3FFFu;
            const uint32_t no = (node << 7) + goff, to = (tag << 7) + goff;
            ct  = *(const float4*)(tagb  + to);
            cr0 = *(const float4*)(nodb0 + no);
            cr1 = *(const float4*)(nodb1 + no);
            cr2 = *(const float4*)(nodb2 + no);
            cr3 = *(const float4*)(nodb3 + no);
        }

        while (j < n) {
            const int nj = j + GPB;
            float4 nt{}, nr0{}, nr1{}, nr2{}, nr3{};
            uint32_t nrec = 0;
            if (nj < n) {
                nrec = recs[nj];
                const uint32_t node = nrec >> 15, tag = (nrec >> 1) & 0x3FFFu;
                const uint32_t no = (node << 7) + goff, to = (tag << 7) + goff;
                nt  = *(const float4*)(tagb  + to);
                nr0 = *(const float4*)(nodb0 + no);
                nr1 = *(const float4*)(nodb1 + no);
                nr2 = *(const float4*)(nodb2 + no);
                nr3 = *(const float4*)(nodb3 + no);
            }

            // fp64 dots of fp32 products: reproduces numpy argmin exactly (absmax 0 r1-r3)
            const double tx = (double)ct.x, ty = (double)ct.y, tz = (double)ct.z, tw = (double)ct.w;
            double q0 = (double)cr0.x*tx + (double)cr0.y*ty + (double)cr0.z*tz + (double)cr0.w*tw;
            double q1 = (double)cr1.x*tx + (double)cr1.y*ty + (double)cr1.z*tz + (double)cr1.w*tw;
            double q2 = (double)cr2.x*tx + (double)cr2.y*ty + (double)cr2.z*tz + (double)cr2.w*tw;
            double q3 = (double)cr3.x*tx + (double)cr3.y*ty + (double)cr3.z*tz + (double)cr3.w*tw;

            #pragma unroll
            for (int off = 1; off < 8; off <<= 1) {   // xor 1,2,4: within the 8-lane group
                q0 += __shfl_xor(q0, off, 64);
                q1 += __shfl_xor(q1, off, 64);
                q2 += __shfl_xor(q2, off, 64);
                q3 += __shfl_xor(q3, off, 64);
            }

            // dist_e = -q_e; argmin first-occurrence == strict "q_e > best"
            double best = q0; int idx = 0;
            if (q1 > best) { best = q1; idx = 1; }
            if (q2 > best) { best = q2; idx = 2; }
            if (q3 > best) { best = q3; idx = 3; }

            const bool  pos = (crec & 1u);
            const float x   = pos ? (float)(-best) : (float)best;
            const float e   = __expf(-fabsf(x));
            local += fmaxf(x, 0.f) + __logf(1.f + e);   // all 8 lanes; /8 at the end

            if (pos && g == 0) {
                const uint32_t node = crec >> 15;
                atomicAdd(&hist[(node - nbase) * NE + idx], 1u);  // LDS atomic, cheap
            }

            j = nj; crec = nrec;
            ct = nt; cr0 = nr0; cr1 = nr1; cr2 = nr2; cr3 = nr3;
        }

        __syncthreads();
        // flush: this block exclusively owns these nodes -> plain read-modify-write
        if (tid < BNODE * NE) {
            const uint32_t cell = nbase * NE + tid;
            const uint32_t h = hist[tid];
            if (h && cell < NODES * NE) out[1 + cell] += (float)h;
        }
        __syncthreads();
    }

    #pragma unroll
    for (int off = 1; off < 64; off <<= 1) local += __shfl_xor(local, off, 64);
    if ((tid & 63) == 0) sm[tid >> 6] = (double)local;
    __syncthreads();
    if (tid == 0) {
        double tot = 0.0;
        #pragma unroll
        for (int w = 0; w < TPB / 64; ++w) tot += sm[w];
        loss_part[blockIdx.x] = tot * 0.125;   // plain store, one per block
    }
}

__global__ __launch_bounds__(TPB) void final_kernel(const double* __restrict__ loss_part,
                                                    float* __restrict__ out, int npart) {
    __shared__ double sm[TPB];
    double v = 0.0;
    for (int i = threadIdx.x; i < npart; i += TPB) v += loss_part[i];
    sm[threadIdx.x] = v;
    __syncthreads();
    for (int s = TPB / 2; s > 0; s >>= 1) {
        if (threadIdx.x < s) sm[threadIdx.x] += sm[threadIdx.x + s];
        __syncthreads();
    }
    if (threadIdx.x == 0) out[0] = (float)sm[0];
}

// ===================== fallback path (r3 kernel, ws-lean) ==================

__global__ __launch_bounds__(TPB) void fb_init(const float* __restrict__ act,
                                               float* __restrict__ out,
                                               double* __restrict__ ws, int npart) {
    int i = blockIdx.x * TPB + threadIdx.x;
    if (i < NODES * NE) out[1 + i] = act[i];
    if (i < npart)      ws[i] = 0.0;
}

__global__ __launch_bounds__(TPB) void fb_main(
    const float* __restrict__ tag_table, const float* __restrict__ node_tables,
    const int* __restrict__ pos_node, const int* __restrict__ pos_tag,
    const int* __restrict__ neg_node, const int* __restrict__ neg_tag,
    float* __restrict__ out, double* __restrict__ ws, int npart)
{
    const int tid = threadIdx.x;
    const int g   = tid & 7;
    const int grp = tid >> 3;
    const uint32_t goff = (uint32_t)g << 4;
    const int total = 2 * NB;
    constexpr int FNB = 2048, FGRP = FNB * GPB;

    const char* tagb  = (const char*)tag_table;
    const char* nodb0 = (const char*)node_tables;
    const char* nodb1 = nodb0 + (size_t)NODES * 128;
    const char* nodb2 = nodb1 + (size_t)NODES * 128;
    const char* nodb3 = nodb2 + (size_t)NODES * 128;

    float local = 0.f;
    for (int s = blockIdx.x * GPB + grp; s < total; s += FGRP) {
        const bool is_pos = s < NB;
        const int  b    = is_pos ? s : s - NB;
        const int  node = is_pos ? pos_node[b] : neg_node[b];
        const int  tag  = is_pos ? pos_tag[b]  : neg_tag[b];
        const uint32_t no = ((uint32_t)node << 7) + goff, to = ((uint32_t)tag << 7) + goff;
        const float4 t  = *(const float4*)(tagb  + to);
        const float4 n0 = *(const float4*)(nodb0 + no);
        const float4 n1 = *(const float4*)(nodb1 + no);
        const float4 n2 = *(const float4*)(nodb2 + no);
        const float4 n3 = *(const float4*)(nodb3 + no);
        const double tx = (double)t.x, ty = (double)t.y, tz = (double)t.z, tw = (double)t.w;
        double q0 = (double)n0.x*tx + (double)n0.y*ty + (double)n0.z*tz + (double)n0.w*tw;
        double q1 = (double)n1.x*tx + (double)n1.y*ty + (double)n1.z*tz + (double)n1.w*tw;
        double q2 = (double)n2.x*tx + (double)n2.y*ty + (double)n2.z*tz + (double)n2.w*tw;
        double q3 = (double)n3.x*tx + (double)n3.y*ty + (double)n3.z*tz + (double)n3.w*tw;
        #pragma unroll
        for (int off = 1; off < 8; off <<= 1) {
            q0 += __shfl_xor(q0, off, 64); q1 += __shfl_xor(q1, off, 64);
            q2 += __shfl_xor(q2, off, 64); q3 += __shfl_xor(q3, off, 64);
        }
        double best = q0; int idx = 0;
        if (q1 > best) { best = q1; idx = 1; }
        if (q2 > best) { best = q2; idx = 2; }
        if (q3 > best) { best = q3; idx = 3; }
        const float x = is_pos ? (float)(-best) : (float)best;
        const float e = __expf(-fabsf(x));
        local += fmaxf(x, 0.f) + __logf(1.f + e);
        if (is_pos && g == 0) atomicAdd(out + 1 + ((size_t)node << 2) + idx, 1.0f);
    }
    #pragma unroll
    for (int off = 1; off < 64; off <<= 1) local += __shfl_xor(local, off, 64);
    __shared__ double sm[TPB / 64];
    if ((tid & 63) == 0) sm[tid >> 6] = (double)local;
    __syncthreads();
    if (tid == 0) {
        double tot = 0.0;
        #pragma unroll
        for (int w = 0; w < TPB / 64; ++w) tot += sm[w];
        atomicAdd(&ws[blockIdx.x & (npart - 1)], tot * 0.125);
    }
}

// ============================== launcher ===================================

extern "C" void kernel_launch(void* const* d_in, const int* in_sizes, int n_in,
                              void* d_out, int out_size, void* d_ws, size_t ws_size,
                              hipStream_t stream) {
    const float* tag_table   = (const float*)d_in[0];
    const float* node_tables = (const float*)d_in[1];
    const float* activate    = (const float*)d_in[2];
    const int*   pos_node    = (const int*)d_in[3];
    const int*   pos_tag     = (const int*)d_in[4];
    const int*   neg_node    = (const int*)d_in[5];
    const int*   neg_tag     = (const int*)d_in[6];
    float* out = (float*)d_out;

    if (ws_size >= WS_NEED) {
        int*      cnt  = (int*)d_ws;
        uint32_t* rec  = (uint32_t*)((char*)d_ws + OFF_REC);
        double*   loss = (double*)((char*)d_ws + OFF_LOSS);

        const int init_blocks = (NODES * NE + TPB - 1) / TPB;
        hipLaunchKernelGGL(init_kernel, dim3(init_blocks), dim3(TPB), 0, stream,
                           activate, out, cnt);
        hipLaunchKernelGGL(scatter_kernel, dim3(2 * NB / TPB), dim3(TPB), 0, stream,
                           pos_node, pos_tag, neg_node, neg_tag, cnt, rec);
        hipLaunchKernelGGL(main_kernel, dim3(NBLK), dim3(TPB), 0, stream,
                           tag_table, node_tables, cnt, rec, out, loss);
        hipLaunchKernelGGL(final_kernel, dim3(1), dim3(TPB), 0, stream, loss, out, NPART);
    } else {
        double* ws = (double*)d_ws;
        int npart = 1;
        while (npart * 2 <= 2048 && (size_t)(npart * 2) * sizeof(double) <= ws_size) npart *= 2;
        const int init_blocks = (NODES * NE + TPB - 1) / TPB;
        hipLaunchKernelGGL(fb_init, dim3(init_blocks), dim3(TPB), 0, stream,
                           activate, out, ws, npart);
        hipLaunchKernelGGL(fb_main, dim3(2048), dim3(TPB), 0, stream,
                           tag_table, node_tables, pos_node, pos_tag, neg_node, neg_tag,
                           out, ws, npart);
        hipLaunchKernelGGL(final_kernel, dim3(1), dim3(TPB), 0, stream, ws, out, npart);
    }
}